// Round 5
// baseline (408.438 us; speedup 1.0000x reference)
//
#include <hip/hip_runtime.h>
#include <cstdint>
#include <cstddef>

// Problem constants
#define Bb 8
#define Tt 2048
#define Cc 1024
#define Dd 1024
#define Mm (Bb*Tt)   // 16384 rows
#define CL 64        // wkv chunk length
#define NCH (Tt/CL)  // 32 chunks

// NOTES:
// - R4: wkv 3-pass parallel scan (318us -> ~40us total).
// - R5: XOR swizzle -> 0 LDS bank conflicts (PMC-verified).
// - R6..R10: every GEMM schedule (coarse/phased x drained/counted) lands
//   713-733 TF, MfmaUtil ~30. Arithmetic: per K-tile/CU MFMA=310cy but LDS
//   traffic 128KB @ ~110-128 B/cy = ~1000cy -> LDS-BYTE-bound. Schedule is
//   irrelevant; must remove LDS bytes.
// - R11: B (2MB weights, L2-resident) pre-packed into MFMA-fragment order
//   ([ntile][ktile][lane][8]; wave fragment = 1KB contiguous) -> loaded
//   straight to VGPRs, coalesced (fixes R9's scatter). LDS now A-only:
//   80KB/tile/CU. A keeps R10's verified ring-3 + pre-swizzle + counted
//   vmcnt(6). B double-buffered in regs (ping-pong, unroll-2, rule #20).
//   Also: wkv_part/chunk vectorized 4d/thread (8B loads, 4 ILP chains).

typedef __bf16  bf16x8  __attribute__((ext_vector_type(8)));
typedef float   floatx4 __attribute__((ext_vector_type(4)));
typedef _Float16 halfx4 __attribute__((ext_vector_type(4)));
typedef unsigned short ushortx4 __attribute__((ext_vector_type(4)));

#define MFMA16(a, b, c) __builtin_amdgcn_mfma_f32_16x16x32_bf16((a), (b), (c), 0, 0, 0)

__device__ __forceinline__ ushort f2bf(float f) {
    unsigned u = __float_as_uint(f);
    u = (u + 0x7FFF + ((u >> 16) & 1)) >> 16;   // RNE
    return (ushort)u;
}
__device__ __forceinline__ float bf2f(ushort u) {
    return __uint_as_float(((unsigned)u) << 16);
}

__device__ __forceinline__ void load_lds16(const void* g, void* l) {
    __builtin_amdgcn_global_load_lds((__attribute__((address_space(1))) void*)(g),
                                     (__attribute__((address_space(3))) void*)(l),
                                     16, 0, 0);
}

#define CFENCE asm volatile("" ::: "memory")
#define BARRIER do { CFENCE; __builtin_amdgcn_s_barrier(); CFENCE; } while (0)

// ---------------- fused mix + time-shift: fp32 x -> bf16 xk,xv,xr ----------------
__global__ __launch_bounds__(256) void prep_mix3(
        const float* __restrict__ x,
        const float* __restrict__ mk, const float* __restrict__ mv,
        const float* __restrict__ mr,
        ushort* __restrict__ xk, ushort* __restrict__ xv, ushort* __restrict__ xr) {
    int i  = blockIdx.x * 256 + threadIdx.x;     // vec8 chunk id, Mm*Cc/8 total
    int cq = i & (Cc / 8 - 1);                   // 128 vec8 per row
    int m  = i >> 7;
    int t  = m & (Tt - 1);
    float xc[8], xp[8];
    *(float4*)&xc[0] = ((const float4*)x)[i * 2];
    *(float4*)&xc[4] = ((const float4*)x)[i * 2 + 1];
    if (t != 0) {
        *(float4*)&xp[0] = ((const float4*)x)[(i - Cc / 8) * 2];
        *(float4*)&xp[4] = ((const float4*)x)[(i - Cc / 8) * 2 + 1];
    } else {
#pragma unroll
        for (int j = 0; j < 8; j++) xp[j] = 0.f;
    }
    float wk[8], wv[8], wr[8];
    *(float4*)&wk[0] = ((const float4*)mk)[cq * 2];
    *(float4*)&wk[4] = ((const float4*)mk)[cq * 2 + 1];
    *(float4*)&wv[0] = ((const float4*)mv)[cq * 2];
    *(float4*)&wv[4] = ((const float4*)mv)[cq * 2 + 1];
    *(float4*)&wr[0] = ((const float4*)mr)[cq * 2];
    *(float4*)&wr[4] = ((const float4*)mr)[cq * 2 + 1];
    ushort ok[8], ov[8], orr[8];
#pragma unroll
    for (int j = 0; j < 8; j++) {
        float d = xc[j] - xp[j];
        ok[j]  = f2bf(xp[j] + d * wk[j]);
        ov[j]  = f2bf(xp[j] + d * wv[j]);
        orr[j] = f2bf(xp[j] + d * wr[j]);
    }
    ((ulonglong2*)xk)[i] = *(const ulonglong2*)ok;
    ((ulonglong2*)xv)[i] = *(const ulonglong2*)ov;
    ((ulonglong2*)xr)[i] = *(const ulonglong2*)orr;
}

// ------- fp32 -> bf16 weight conversion + MFMA-fragment packing -------
// Packed layout per matrix: [ntile=n/16][ktile=k/32][lane=quad*16+fr][e=0..7]
// where element (n,k): fr=n&15, quad=(k&31)>>3, e=k&7.
// A wave's B-fragment (one ntile, one ktile) = 64 lanes x 16B = 1KB contiguous.
__global__ __launch_bounds__(256) void cvt_w(
        const float* __restrict__ wk, const float* __restrict__ wv,
        const float* __restrict__ wr, const float* __restrict__ wo,
        ushort* __restrict__ ok, ushort* __restrict__ ov,
        ushort* __restrict__ orr, ushort* __restrict__ oo) {
    int i = blockIdx.x * 256 + threadIdx.x;       // 4 * 64 * 128 * 16 threads
    int fr  = i & 15;
    int c8  = (i >> 4) & 127;                     // c-group of 8
    int nhi = (i >> 11) & 63;                     // n-tile
    int sel = i >> 17;
    const float* s = sel == 0 ? wk : sel == 1 ? wv : sel == 2 ? wr : wo;
    ushort* d      = sel == 0 ? ok : sel == 1 ? ov : sel == 2 ? orr : oo;
    int n = nhi * 16 + fr;
    const float4* src = (const float4*)(s + (size_t)n * Cc + c8 * 8);
    float4 f0 = src[0], f1 = src[1];
    ushort o[8];
    o[0] = f2bf(f0.x); o[1] = f2bf(f0.y); o[2] = f2bf(f0.z); o[3] = f2bf(f0.w);
    o[4] = f2bf(f1.x); o[5] = f2bf(f1.y); o[6] = f2bf(f1.z); o[7] = f2bf(f1.w);
    // ull2 index = ((nhi*32 + (c8>>2)) * 64) + (c8&3)*16 + fr
    int idx = (nhi * 32 + (c8 >> 2)) * 64 + (c8 & 3) * 16 + fr;
    ((ulonglong2*)d)[idx] = *(const ulonglong2*)o;
}

// ======== R11 GEMM core: 256x256 tile, BK=32, A in LDS ring-3, B in regs ========
// 512 threads = 8 waves (2m x 4n); per-wave output 128x64, acc[8][4] floatx4.
// LDS: A only, 3 slots x [256][32] bf16 (16 KB each, 48 KB total).
//   Stage/read swizzle identical to R10 (PMC-verified conflict-free family).
// B: packed fragments (see cvt_w) loaded global->VGPR, 1KB/wave coalesced,
//   double-buffered one tile ahead via ping-pong regs (loop unrolled x2).
// Per tile T: {load B(T+1) -> 4 dwordx4 | stage A(T+2) -> 2 gload_lds |
//   8 ds_read_b128 | 32 MFMA (setprio) | vmcnt(6) counted | 1 barrier}.
// vmcnt audit at tail of T: outstanding = A(T+1)(2) B(T+1)(4) A(T+2)(2);
// vmcnt(6) drains exactly A(T+1). Compiler's own reg-waits for B never
// over-drain the A pipeline (B(T)'s younger set is 6).
struct GemmR11 {
    floatx4 acc[8][4];
    int quad, fr, wm, wn;

    __device__ __forceinline__ void run(
            const ushort* __restrict__ A, const ushort* __restrict__ Bp,
            long tm, long tn, int Kdim, __bf16* LDSb) {
        const int tid  = threadIdx.x;
        const int lane = tid & 63;
        quad = lane >> 4;
        fr   = lane & 15;
        const int wave = tid >> 6;
        wm = (wave >> 2) * 128;          // m-half: 0 or 128
        wn = (wave & 3) * 64;            // n-col:  0,64,128,192
        const int goff = (quad ^ ((fr >> 1) & 3)) * 8;   // A read granule
        const int NKT  = Kdim >> 5;      // k-tiles of 32

        // A staging (R10-verified): row tid>>2, pre-swizzled source granule
        const int srow = tid >> 2;               // 0..127
        const int scol = ((tid & 3) ^ ((tid >> 3) & 3)) * 8;
        const int wlds = wave * 512;             // wave-uniform LDS elem base
        const ushort* Ag0 = A + (tm + srow) * (long)Kdim + scol;
        const ushort* Ag1 = Ag0 + 128 * (long)Kdim;

        auto stageA = [&](int buf, long ko) {
            __bf16* d = LDSb + buf * 8192;
            load_lds16(Ag0 + ko, d + wlds);
            load_lds16(Ag1 + ko, d + 4096 + wlds);
        };

        // B packed fragment base for this wave
        const ushort* Bq = Bp + ((long)((tn + wn) >> 4)) * NKT * 512 + lane * 8;

        floatx4 zero = {0.f, 0.f, 0.f, 0.f};
#pragma unroll
        for (int ai = 0; ai < 8; ai++)
#pragma unroll
            for (int nj = 0; nj < 4; nj++) acc[ai][nj] = zero;

        const int NT = NKT;              // BK == 32

        // prologue: stage A(0),A(1); load B(0); drain A(0) only
        stageA(0, 0);
        stageA(1, 32);
        bf16x8 bA[4], bB[4];
#pragma unroll
        for (int ni = 0; ni < 4; ni++)
            bA[ni] = *(const bf16x8*)(Bq + (long)ni * NKT * 512);
        asm volatile("s_waitcnt vmcnt(6)" ::: "memory");
        BARRIER;

        int slot = 0, snext = 2;

#define R11_BODY(T, BC, BN)                                                   \
        {                                                                     \
            const __bf16* Ab = LDSb + slot * 8192;                            \
            const bool pfB = (T) + 1 < NT;                                    \
            const bool pfA = (T) + 2 < NT;                                    \
            if (pfB) {                                                        \
                _Pragma("unroll")                                             \
                for (int ni = 0; ni < 4; ni++)                                \
                    BN[ni] = *(const bf16x8*)(Bq + ((long)ni * NKT + (T) + 1) * 512); \
            }                                                                 \
            if (pfA) stageA(snext, (long)((T) + 2) * 32);                     \
            bf16x8 a_[8];                                                     \
            _Pragma("unroll")                                                 \
            for (int i = 0; i < 8; i++)                                       \
                a_[i] = *(const bf16x8*)&Ab[(wm + i * 16 + fr) * 32 + goff];  \
            __builtin_amdgcn_s_setprio(1);                                    \
            _Pragma("unroll")                                                 \
            for (int i = 0; i < 8; i++) {                                     \
                acc[i][0] = MFMA16(a_[i], BC[0], acc[i][0]);                  \
                acc[i][1] = MFMA16(a_[i], BC[1], acc[i][1]);                  \
                acc[i][2] = MFMA16(a_[i], BC[2], acc[i][2]);                  \
                acc[i][3] = MFMA16(a_[i], BC[3], acc[i][3]);                  \
            }                                                                 \
            __builtin_amdgcn_s_setprio(0);                                    \
            if (pfB) {                                                        \
                if (pfA) asm volatile("s_waitcnt vmcnt(6)" ::: "memory");     \
                else     asm volatile("s_waitcnt vmcnt(4)" ::: "memory");     \
                BARRIER;                                                      \
            }                                                                 \
            slot  = (slot  + 1 == 3) ? 0 : slot  + 1;                         \
            snext = (snext + 1 == 3) ? 0 : snext + 1;                         \
        }

        for (int T = 0; T < NT; T += 2) {    // NT even (K=1024 -> 32)
            R11_BODY(T,     bA, bB);
            R11_BODY(T + 1, bB, bA);
        }
#undef R11_BODY
    }
};

// ---------------- single GEMM (used for Wo, and serial fallback) ----------------
// MODE: 0 = fp32 out, 1 = bf16 out, 2 = bf16 out + sigmoid, 3 = fp16 out
// Bw is PACKED (cvt_w layout). grid (64, 4), XCD-chunked swizzle.
template<int MODE>
__global__ __launch_bounds__(512, 2) void gemm_nt(
        const ushort* __restrict__ A, const ushort* __restrict__ Bw,
        void* __restrict__ Co, int Ndim, int Kdim) {
    __shared__ __attribute__((aligned(16))) __bf16 LDSb[3 * 8192];  // 48 KB
    const int orig = blockIdx.y * 64 + blockIdx.x;        // 0..255
    const int L    = (orig & 7) * 32 + (orig >> 3);       // contiguous per XCD
    const long tm = (long)(L >> 2) * 256;
    const long tn = (long)(L & 3) * 256;
    GemmR11 g;
    g.run(A, Bw, tm, tn, Kdim, LDSb);
#pragma unroll
    for (int ai = 0; ai < 8; ai++)
#pragma unroll
        for (int nj = 0; nj < 4; nj++)
#pragma unroll
            for (int r = 0; r < 4; r++) {
                long grow = tm + g.wm + ai * 16 + g.quad * 4 + r;
                long gcol = tn + g.wn + nj * 16 + g.fr;
                float v = g.acc[ai][nj][r];
                if (MODE == 2) v = 1.f / (1.f + __expf(-v));
                if (MODE == 0)      ((float*)Co)[grow * Ndim + gcol] = v;
                else if (MODE == 3) ((_Float16*)Co)[grow * Ndim + gcol] = (_Float16)v;
                else                ((ushort*)Co)[grow * Ndim + gcol] = f2bf(v);
            }
}

// ---------------- merged 3-projection GEMM (needs ws >= 204 MB) ----------------
// grid (64, 12); proj-major logical order, chunked 96/XCD for A-panel L2 reuse.
// Weights PACKED.
__global__ __launch_bounds__(512, 2) void gemm3_nt(
        const ushort* __restrict__ xk, const ushort* __restrict__ xv,
        const ushort* __restrict__ xr,
        const ushort* __restrict__ wk, const ushort* __restrict__ wv,
        const ushort* __restrict__ wr,
        _Float16* __restrict__ kb, ushort* __restrict__ vb,
        ushort* __restrict__ sb) {
    __shared__ __attribute__((aligned(16))) __bf16 LDSb[3 * 8192];  // 48 KB
    const int orig = blockIdx.y * 64 + blockIdx.x;        // 0..767
    const int L    = (orig & 7) * 96 + (orig >> 3);
    const int proj = L >> 8;
    const int rem  = L & 255;
    const long tm = (long)(rem >> 2) * 256;
    const long tn = (long)(rem & 3) * 256;
    const ushort* A  = proj == 0 ? xk : proj == 1 ? xv : xr;
    const ushort* Bw = proj == 0 ? wk : proj == 1 ? wv : wr;
    GemmR11 g;
    g.run(A, Bw, tm, tn, Cc, LDSb);
#pragma unroll
    for (int ai = 0; ai < 8; ai++)
#pragma unroll
        for (int nj = 0; nj < 4; nj++)
#pragma unroll
            for (int r = 0; r < 4; r++) {
                long grow = tm + g.wm + ai * 16 + g.quad * 4 + r;
                long gcol = tn + g.wn + nj * 16 + g.fr;
                long off = grow * Dd + gcol;
                float v = g.acc[ai][nj][r];
                if (proj == 0)      kb[off] = (_Float16)v;
                else if (proj == 1) vb[off] = f2bf(v);
                else                sb[off] = f2bf(1.f / (1.f + __expf(-v)));
            }
}

// ---------------- WKV: 3-pass chunked parallel scan (4 d/thread) ----------------
__global__ __launch_bounds__(256) void wkv_part(
        const _Float16* __restrict__ kb, const ushort* __restrict__ vb,
        const float* __restrict__ decay,
        float* __restrict__ pa, float* __restrict__ pb) {
    int gid = blockIdx.x * 256 + threadIdx.x;   // 0..B*NCH*D/4-1
    int d0 = (gid & 255) * 4;
    int c  = (gid >> 8) & (NCH - 1);
    int b  = gid >> 13;
    float4 dec = *(const float4*)(decay + d0);
    float ew[4] = { __expf(-__expf(dec.x)), __expf(-__expf(dec.y)),
                    __expf(-__expf(dec.z)), __expf(-__expf(dec.w)) };
    size_t base = ((size_t)b * Tt + (size_t)c * CL) * Dd + d0;
    float a[4] = {0.f, 0.f, 0.f, 0.f}, bs[4] = {0.f, 0.f, 0.f, 0.f};
    for (int t = 0; t < CL; ++t) {
        size_t idx = base + (size_t)t * Dd;
        halfx4   kv = *(const halfx4*)(kb + idx);
        ushortx4 vv = *(const ushortx4*)(vb + idx);
#pragma unroll
        for (int j = 0; j < 4; j++) {
            float ek = __expf((float)kv[j]);
            a[j]  = ew[j] * a[j]  + ek * bf2f(vv[j]);
            bs[j] = ew[j] * bs[j] + ek;
        }
    }
    int sidx = c * (Bb * Dd) + b * Dd + d0;     // [c][b][d]
    *(float4*)(pa + sidx) = *(const float4*)a;
    *(float4*)(pb + sidx) = *(const float4*)bs;
}

__global__ __launch_bounds__(256) void wkv_prefix(
        const float* __restrict__ pa, const float* __restrict__ pb,
        const float* __restrict__ decay,
        float* __restrict__ sa, float* __restrict__ sb) {
    int gid = blockIdx.x * 256 + threadIdx.x;   // 0..B*D-1
    int d = gid & (Dd - 1);
    float ewL = __expf(-__expf(decay[d]) * (float)CL);  // ew^CL, direct
    float ca = 0.f, cb = 0.f;
#pragma unroll
    for (int c = 0; c < NCH; c++) {
        int idx = c * (Bb * Dd) + gid;
        sa[idx] = ca; sb[idx] = cb;
        ca = ewL * ca + pa[idx];
        cb = ewL * cb + pb[idx];
    }
}

__global__ __launch_bounds__(256) void wkv_chunk(
        const _Float16* __restrict__ kb, const ushort* __restrict__ vb,
        const ushort* __restrict__ sr,
        const float* __restrict__ decay, const float* __restrict__ tf,
        const float* __restrict__ sa, const float* __restrict__ sb,
        ushort* __restrict__ rw) {
    int gid = blockIdx.x * 256 + threadIdx.x;
    int d0 = (gid & 255) * 4;
    int c  = (gid >> 8) & (NCH - 1);
    int b  = gid >> 13;
    float4 dec = *(const float4*)(decay + d0);
    float4 tff = *(const float4*)(tf + d0);
    float ew[4] = { __expf(-__expf(dec.x)), __expf(-__expf(dec.y)),
                    __expf(-__expf(dec.z)), __expf(-__expf(dec.w)) };
    float eu[4] = { __expf(tff.x), __expf(tff.y), __expf(tff.z), __expf(tff.w) };
    int sidx = c * (Bb * Dd) + b * Dd + d0;
    float a[4], bs[4];
    *(float4*)a  = *(const float4*)(sa + sidx);
    *(float4*)bs = *(const float4*)(sb + sidx);
    size_t base = ((size_t)b * Tt + (size_t)c * CL) * Dd + d0;
    for (int t = 0; t < CL; ++t) {
        size_t idx = base + (size_t)t * Dd;
        halfx4   kv = *(const halfx4*)(kb + idx);
        ushortx4 vv = *(const ushortx4*)(vb + idx);
        ushortx4 rv = *(const ushortx4*)(sr + idx);
        ushortx4 ov;
#pragma unroll
        for (int j = 0; j < 4; j++) {
            float ek  = __expf((float)kv[j]);
            float ekv = ek * bf2f(vv[j]);
            float out = (eu[j] * ekv + a[j]) / (eu[j] * ek + bs[j]);
            a[j]  = ew[j] * a[j]  + ekv;
            bs[j] = ew[j] * bs[j] + ek;
            ov[j] = f2bf(bf2f(rv[j]) * out);
        }
        *(ushortx4*)(rw + idx) = ov;
    }
}

extern "C" void kernel_launch(void* const* d_in, const int* in_sizes, int n_in,
                              void* d_out, int out_size, void* d_ws, size_t ws_size,
                              hipStream_t stream) {
    (void)in_sizes; (void)n_in; (void)out_size;
    const float* x  = (const float*)d_in[0];
    const float* td = (const float*)d_in[1];
    const float* tf = (const float*)d_in[2];
    const float* mk = (const float*)d_in[3];
    const float* mv = (const float*)d_in[4];
    const float* mr = (const float*)d_in[5];
    const float* Wk = (const float*)d_in[6];
    const float* Wv = (const float*)d_in[7];
    const float* Wr = (const float*)d_in[8];
    const float* Wo = (const float*)d_in[9];
    float* out = (float*)d_out;

    const size_t xsz = (size_t)Mm * Cc * 2;           // 32 MB
    const size_t wsz = (size_t)Dd * Cc * 2;           // 2 MB
    const size_t ssz = (size_t)Bb * NCH * Dd * 4;     // 1 MB
    const size_t need_merged = 6 * xsz + 4 * wsz + 4 * ssz;   // ~204 MB

    char* p = (char*)d_ws;
    auto take = [&](size_t n) { char* r = p; p += n; return r; };
    ushort*   xk = (ushort*)take(xsz);
    ushort*   xv = (ushort*)take(xsz);
    ushort*   xr = (ushort*)take(xsz);
    _Float16* kb = (_Float16*)take(xsz);
    const bool merged = ws_size >= need_merged;
    ushort *vb, *sb, *rw;
    if (merged) {
        vb = (ushort*)take(xsz);
        sb = (ushort*)take(xsz);
        rw = xk;                       // xk dead after gemm3
    } else {
        vb = xk;                       // serial aliasing (R5 layout)
        sb = xv;
        rw = xr;
    }
    ushort* wk = (ushort*)take(wsz);
    ushort* wv = (ushort*)take(wsz);
    ushort* wr = (ushort*)take(wsz);
    ushort* wo = (ushort*)take(wsz);
    float*  pa = (float*)take(ssz);
    float*  pb = (float*)take(ssz);
    float*  sa = (float*)take(ssz);
    float*  sbst = (float*)take(ssz);

    dim3 g1(Mm / 256, Dd / 256);          // (64, 4)
    dim3 g2(Mm / 256, Cc / 256);          // (64, 4)
    dim3 g3(Mm / 256, 3 * Dd / 256);      // (64, 12)
    const int wkv_grid = (Bb * NCH * Dd / 4) / 256;   // 256

    cvt_w<<<2048, 256, 0, stream>>>(Wk, Wv, Wr, Wo, wk, wv, wr, wo);
    prep_mix3<<<Mm * Cc / 8 / 256, 256, 0, stream>>>(x, mk, mv, mr, xk, xv, xr);

    if (merged) {
        gemm3_nt<<<g3, 512, 0, stream>>>(xk, xv, xr, wk, wv, wr, kb, vb, sb);
    } else {
        gemm_nt<3><<<g1, 512, 0, stream>>>(xk, wk, kb, Dd, Cc);
        gemm_nt<1><<<g1, 512, 0, stream>>>(xv, wv, vb, Dd, Cc);
        gemm_nt<2><<<g1, 512, 0, stream>>>(xr, wr, sb, Dd, Cc);
    }

    wkv_part  <<<wkv_grid, 256, 0, stream>>>(kb, vb, td, pa, pb);
    wkv_prefix<<<(Bb * Dd) / 256, 256, 0, stream>>>(pa, pb, td, sa, sbst);
    wkv_chunk <<<wkv_grid, 256, 0, stream>>>(kb, vb, sb, td, tf, sa, sbst, rw);

    gemm_nt<0><<<g2, 512, 0, stream>>>(rw, wo, out, Cc, Dd);
}